// Round 10
// baseline (270.988 us; speedup 1.0000x reference)
//
#include <hip/hip_runtime.h>

#define NB 8
#define NP 24564
#define NCLS 80          // foreground classes
#define TOPK 400
#define KEEPK 200
#define OUTS 19
#define NCELL (OUTS * OUTS)   // 361
#define DETN (NCLS * TOPK)    // 32000 per batch
#define CKS 32008             // compact-key stride per batch (16B-aligned)
#define ROWS 128
#define CHUNKS ((NP + ROWS - 1) / ROWS)   // 192
#define CAP 1024
#define T0 0.972f   // collection gate: E[count]=688 sd 26 -> count in [400,1024] w.h.p.
#define NT 512      // threads per block for kNms/kC/kA (8 waves)
#define LCAP 24     // per (chunk,class) LDS capacity: P(Poisson(3.58)>24) ~ 1e-12
#define CSTR 16     // counter stride in u32 (64B = own cache line, kills atomic convoy)
#define SUBS 8      // score buckets per (b,c); bucket monotone in key
#define SUBCAP 128  // slots per bucket; E=86 sd 9.3 -> P(ovf)~3e-6/bucket (gflag covers)
#define WTASK 2704  // packed triangular IoU words: sum_{r<400} (r/32+1)
#define TILN 676    // 4-row x 32-col IoU tiles: sum_{g<100} (g/8+1)
// Skewed LDS index: for j=32w+jj, bank(4B)=(w+jj)%32 (conflict-free across w),
// bank-group(16B)=(w+jj)%8 (<=2-way = free). Same w -> same addr -> broadcast.
#define SKW(i) ((unsigned)(i) + ((unsigned)(i) >> 5))
#define SELN (TOPK + (TOPK >> 5) + 4)   // 416

__device__ __forceinline__ unsigned f2ord(float f) {
    unsigned u = __float_as_uint(f);
    return (u & 0x80000000u) ? ~u : (u | 0x80000000u);
}
__device__ __forceinline__ float ord2f(unsigned k) {
    unsigned u = (k & 0x80000000u) ? (k & 0x7fffffffu) : ~k;
    return __uint_as_float(u);
}
// 1024 bins over key top-16-bits; valid scores (0.01,1] map to [0x23,0x380].
__device__ __forceinline__ unsigned bin16(unsigned key) {
    int b = (int)(key >> 16) - 0xBC00;
    b = b < 0 ? 0 : (b > 1023 ? 1023 : b);
    return (unsigned)b;
}
// score bucket: monotone non-decreasing in v (float sub/mul/trunc all monotone)
__device__ __forceinline__ int sbucket(float v) {
    int bkt = (int)((v - T0) * 285.7142f);   // 8 / 0.028
    return bkt < 0 ? 0 : (bkt > 7 ? 7 : bkt);
}

__device__ __forceinline__ unsigned long long shfl_xor_u64(unsigned long long v, int mask) {
    unsigned lo = (unsigned)__shfl_xor((int)(unsigned)v, mask);
    unsigned hi = (unsigned)__shfl_xor((int)(v >> 32), mask);
    return ((unsigned long long)hi << 32) | lo;
}

// Wave-local bitonic sort of 128 elems (2/lane, e0=2*lane) descending.
// All exchanges intra-wave via shfl_xor -> ZERO barriers.
__device__ __forceinline__ void wave_sort128(unsigned long long& a0, unsigned long long& a1,
                                             unsigned lane) {
    const unsigned e0 = 2u * lane;
#pragma unroll
    for (unsigned k = 2; k <= 128; k <<= 1) {
#pragma unroll
        for (unsigned j = k >> 1; j >= 2; j >>= 1) {
            unsigned long long b0 = shfl_xor_u64(a0, (int)(j >> 1));
            unsigned long long b1 = shfl_xor_u64(a1, (int)(j >> 1));
            bool km = ((e0 & k) == 0u) ^ ((e0 & j) != 0u);
            a0 = km ? (a0 > b0 ? a0 : b0) : (a0 < b0 ? a0 : b0);
            a1 = km ? (a1 > b1 ? a1 : b1) : (a1 < b1 ? a1 : b1);
        }
        {   // j == 1: in-thread
            bool dir = ((e0 & k) == 0u);
            unsigned long long mx = a0 > a1 ? a0 : a1;
            unsigned long long mn = a0 > a1 ? a1 : a0;
            a0 = dir ? mx : mn;
            a1 = dir ? mn : mx;
        }
    }
}

// Block-wide register bitonic (kC + fallback path only).
__device__ __forceinline__ void regsort1024(unsigned long long& a0, unsigned long long& a1,
                                            unsigned long long* sc, unsigned t) {
    const unsigned e0 = 2u * t;
#pragma unroll
    for (unsigned k = 2; k <= 1024; k <<= 1) {
#pragma unroll
        for (unsigned j = k >> 1; j >= 128; j >>= 1) {   // cross-wave via LDS
            sc[e0] = a0; sc[e0 + 1] = a1;
            __syncthreads();
            unsigned p0 = e0 ^ j;
            unsigned long long b0 = sc[p0], b1 = sc[p0 + 1];
            bool km = ((e0 & k) == 0u) ^ ((e0 & j) != 0u);
            a0 = km ? (a0 > b0 ? a0 : b0) : (a0 < b0 ? a0 : b0);
            a1 = km ? (a1 > b1 ? a1 : b1) : (a1 < b1 ? a1 : b1);
            __syncthreads();
        }
#pragma unroll
        for (unsigned j = ((k >> 1) < 64u ? (k >> 1) : 64u); j >= 2; j >>= 1) { // intra-wave
            unsigned long long b0 = shfl_xor_u64(a0, (int)(j >> 1));
            unsigned long long b1 = shfl_xor_u64(a1, (int)(j >> 1));
            bool km = ((e0 & k) == 0u) ^ ((e0 & j) != 0u);
            a0 = km ? (a0 > b0 ? a0 : b0) : (a0 < b0 ? a0 : b0);
            a1 = km ? (a1 > b1 ? a1 : b1) : (a1 < b1 ? a1 : b1);
        }
        {   // j == 1: in-thread
            bool dir = ((e0 & k) == 0u);
            unsigned long long mx = a0 > a1 ? a0 : a1;
            unsigned long long mn = a0 > a1 ? a1 : a0;
            a0 = dir ? mx : mn;
            a1 = dir ? mn : mx;
        }
    }
}

// LDS bitonic for the (near-never) exact fallback path only.
__device__ __forceinline__ void bitonic_desc(unsigned long long* cand, unsigned S, int tid) {
    for (unsigned k = 2; k <= S; k <<= 1)
        for (unsigned j = k >> 1; j; j >>= 1) {
            for (unsigned i = tid; i < S; i += NT) {
                unsigned l = i ^ j;
                if (l > i) {
                    unsigned long long a = cand[i], bq = cand[l];
                    bool sw = ((i & k) == 0) ? (a < bq) : (a > bq);
                    if (sw) { cand[i] = bq; cand[l] = a; }
                }
            }
            __syncthreads();
        }
}

// ------- kZ: zero counters + overflow flags --------------------------------
__global__ __launch_bounds__(256) void kZ(unsigned* __restrict__ ccnt,
                                          unsigned* __restrict__ gflag,
                                          unsigned* __restrict__ kcnt) {
    int t = blockIdx.x * 256 + threadIdx.x;
    for (int i = t; i < NB * NCLS * SUBS * CSTR; i += gridDim.x * 256) ccnt[i] = 0u;
    if (t < NB * NCLS) gflag[t] = 0u;
    if (t < NB * 16) kcnt[t] = 0u;
}

// ------- kA: ballot-parallel bucket ranks; 8 unguarded overlapped atomics --
// Each (b,c) slab = 8 score buckets x 128 slots. Per-bucket ranks computed
// with ballots during collection (no serial loop); the per-class thread
// issues all 8 atomics unconditionally so their latencies overlap.
__global__ __launch_bounds__(NT) void kA(const float* __restrict__ x,
                                         float4* __restrict__ boxes,
                                         unsigned long long* __restrict__ pcand,
                                         unsigned* __restrict__ ccnt,
                                         unsigned* __restrict__ gflag) {
    __shared__ float tile[ROWS * 93];
    __shared__ unsigned long long list[NCLS * LCAP];
    __shared__ unsigned lcnt[NCLS];
    __shared__ unsigned short lcntB[NCLS * SUBS];
    __shared__ unsigned lbaseB[NCLS * SUBS];
    __shared__ unsigned short posArr[NCLS * LCAP];

    int blk = blockIdx.x;
    int b = blk / CHUNKS, chunk = blk % CHUNKS;
    int p0 = chunk * ROWS;
    int nrows = NP - p0; if (nrows > ROWS) nrows = ROWS;   // last chunk: 116 (%4==0)
    const float* src = x + (size_t)(b * NP + p0) * 93;
    int total4 = (nrows * 93) >> 2;
    const float4* s4 = (const float4*)src;
    float4* t4 = (float4*)tile;
    for (int e = threadIdx.x; e < total4; e += NT) t4[e] = s4[e];
    __syncthreads();

    int lane = threadIdx.x & 63;
    int cg = threadIdx.x >> 6;               // 8 waves
    for (int c = cg; c < NCLS; c += (NT / 64)) {   // c uniform per wave, unique per block
        unsigned cnt = 0u;
        unsigned n0 = 0, n1 = 0, n2 = 0, n3 = 0, n4 = 0, n5 = 0, n6 = 0, n7 = 0;
        for (int h = 0; h < 2; ++h) {        // two 64-row halves per chunk
            int row = h * 64 + lane;
            float v = (row < nrows) ? tile[row * 93 + 5 + c] : -1.0f;
            bool pred = v > T0;
            int bkt = pred ? sbucket(v) : -1;
            unsigned long long bal = __ballot(pred);
            unsigned myR = 0u;
#define BB(B, NB_) { \
            unsigned long long balB = __ballot(bkt == (B)); \
            if (bkt == (B)) myR = NB_ + (unsigned)__popcll(balB & ((1ull << lane) - 1ull)); \
            NB_ += (unsigned)__popcll(balB); }
            BB(0, n0) BB(1, n1) BB(2, n2) BB(3, n3)
            BB(4, n4) BB(5, n5) BB(6, n6) BB(7, n7)
#undef BB
            if (pred) {
                unsigned r = cnt + (unsigned)__popcll(bal & ((1ull << lane) - 1ull));
                if (r < LCAP) {
                    list[c * LCAP + r] =
                        ((unsigned long long)f2ord(v) << 32) |
                        (unsigned)(~(unsigned)(p0 + row));
                    posArr[c * LCAP + r] =
                        (unsigned short)((unsigned)bkt * SUBCAP + myR);
                }
            }
            cnt += (unsigned)__popcll(bal);
        }
        if (lane == 0) {
            lcnt[c] = cnt;
            lcntB[c * SUBS + 0] = (unsigned short)n0;
            lcntB[c * SUBS + 1] = (unsigned short)n1;
            lcntB[c * SUBS + 2] = (unsigned short)n2;
            lcntB[c * SUBS + 3] = (unsigned short)n3;
            lcntB[c * SUBS + 4] = (unsigned short)n4;
            lcntB[c * SUBS + 5] = (unsigned short)n5;
            lcntB[c * SUBS + 6] = (unsigned short)n6;
            lcntB[c * SUBS + 7] = (unsigned short)n7;
        }
    }
    __syncthreads();

    // waves 2-3: 8 UNGUARDED atomics per class, issued back-to-back so the
    // latencies overlap (atomicAdd of 0 is harmless). Hidden under decode.
    if (threadIdx.x >= 128 && threadIdx.x < 128 + NCLS) {
        int c = threadIdx.x - 128;
        unsigned n = lcnt[c];
        unsigned nb0 = lcntB[c * SUBS + 0], nb1 = lcntB[c * SUBS + 1];
        unsigned nb2 = lcntB[c * SUBS + 2], nb3 = lcntB[c * SUBS + 3];
        unsigned nb4 = lcntB[c * SUBS + 4], nb5 = lcntB[c * SUBS + 5];
        unsigned nb6 = lcntB[c * SUBS + 6], nb7 = lcntB[c * SUBS + 7];
        unsigned* cp = &ccnt[(b * NCLS + c) * SUBS * CSTR];
        unsigned o0 = atomicAdd(cp + 0 * CSTR, nb0);
        unsigned o1 = atomicAdd(cp + 1 * CSTR, nb1);
        unsigned o2 = atomicAdd(cp + 2 * CSTR, nb2);
        unsigned o3 = atomicAdd(cp + 3 * CSTR, nb3);
        unsigned o4 = atomicAdd(cp + 4 * CSTR, nb4);
        unsigned o5 = atomicAdd(cp + 5 * CSTR, nb5);
        unsigned o6 = atomicAdd(cp + 6 * CSTR, nb6);
        unsigned o7 = atomicAdd(cp + 7 * CSTR, nb7);
        unsigned ovf = (unsigned)(n > LCAP);
        ovf |= (o0 + nb0 > SUBCAP) | (o1 + nb1 > SUBCAP) | (o2 + nb2 > SUBCAP)
             | (o3 + nb3 > SUBCAP) | (o4 + nb4 > SUBCAP) | (o5 + nb5 > SUBCAP)
             | (o6 + nb6 > SUBCAP) | (o7 + nb7 > SUBCAP);
        if (ovf) gflag[b * NCLS + c] = 1u;   // benign race (same value)
        lbaseB[c * SUBS + 0] = o0; lbaseB[c * SUBS + 1] = o1;
        lbaseB[c * SUBS + 2] = o2; lbaseB[c * SUBS + 3] = o3;
        lbaseB[c * SUBS + 4] = o4; lbaseB[c * SUBS + 5] = o5;
        lbaseB[c * SUBS + 6] = o6; lbaseB[c * SUBS + 7] = o7;
    }
    // waves 0-1 (concurrent with the atomics): decode + store boxes
    if (threadIdx.x < nrows) {
        const float* r = tile + threadIdx.x * 93;
        float l0 = r[0], l1 = r[1], l2 = r[2], l3 = r[3];
        float px1 = r[85], py1 = r[86], px2 = r[87], py2 = r[88];
        float v0 = r[89], v1 = r[90], v2 = r[91], v3 = r[92];
        float pw = px2 - px1, ph = py2 - py1;
        float pcx = 0.5f * (px2 + px1), pcy = 0.5f * (py2 + py1);
        float cx = l0 * pw * v0 + pcx;
        float cy = l1 * pw * v1 + pcy;      // reference uses pw here too
        float w = expf(l2 * v2) * pw;
        float h = expf(l3 * v3) * ph;
        float x1 = fminf(fmaxf(cx - 0.5f * w, 0.f), 1.f);
        float y1 = fminf(fmaxf(cy - 0.5f * h, 0.f), 1.f);
        float x2 = fminf(fmaxf(cx + 0.5f * w, 0.f), 1.f);
        float y2 = fminf(fmaxf(cy + 0.5f * h, 0.f), 1.f);
        boxes[(size_t)b * NP + p0 + threadIdx.x] = make_float4(x1, y1, x2, y2);
    }
    __syncthreads();

    for (int idx = threadIdx.x; idx < NCLS * LCAP; idx += NT) {
        int c = idx / LCAP, i = idx - c * LCAP;
        unsigned n = lcnt[c]; if (n > LCAP) n = LCAP;
        if ((unsigned)i < n) {
            unsigned pr = (unsigned)posArr[idx];
            unsigned bkt = pr >> 7;             // SUBCAP = 128
            unsigned pos = lbaseB[c * SUBS + bkt] + (pr & 127u);
            if (pos < SUBCAP)   // overflow -> gflag -> exact fallback path
                pcand[((size_t)(b * NCLS + c) << 10) + bkt * SUBCAP + pos] = list[idx];
        }
    }
}

// --- exact fallback select: strided masked read of x, hist1024 + refine ----
__device__ void select_strided(const float* __restrict__ src, unsigned needed,
                               unsigned long long* cand,
                               unsigned* hist, unsigned* aux, unsigned* scal,
                               int tid) {
    for (int i = tid; i < 1024; i += NT) hist[i] = 0u;
    if (tid == 0) { scal[0] = 0u; scal[1] = 0u; scal[2] = 0u; scal[3] = 0u; }
    __syncthreads();
    for (int p = tid; p < NP; p += NT) {
        float v = src[(size_t)p * 93];
        float m = (v > 0.01f) ? v : -1.0f;
        atomicAdd(&hist[bin16(f2ord(m))], 1u);
    }
    __syncthreads();
    unsigned h0 = 0, h1 = 0, h2 = 0, h3 = 0;
    if (tid < 256) {
        h0 = hist[4 * tid]; h1 = hist[4 * tid + 1];
        h2 = hist[4 * tid + 2]; h3 = hist[4 * tid + 3];
        aux[tid] = h0 + h1 + h2 + h3;
    }
    __syncthreads();
    for (int d = 1; d < 256; d <<= 1) {
        unsigned v = 0u;
        if (tid < 256 && tid + d < 256) v = aux[tid + d];
        __syncthreads();
        if (tid < 256) aux[tid] += v;
        __syncthreads();
    }
    if (tid < 256) {
        unsigned above = (tid < 255) ? aux[tid + 1] : 0u;
        unsigned s3 = above + h3, s2 = s3 + h2, s1 = s2 + h1, s0 = s1 + h0;
        if (s0 >= needed && s1 < needed) { scal[0] = 4 * tid;     scal[1] = s1;    scal[2] = s0; }
        if (s1 >= needed && s2 < needed) { scal[0] = 4 * tid + 1; scal[1] = s2;    scal[2] = s1; }
        if (s2 >= needed && s3 < needed) { scal[0] = 4 * tid + 2; scal[1] = s3;    scal[2] = s2; }
        if (s3 >= needed && above < needed) { scal[0] = 4 * tid + 3; scal[1] = above; scal[2] = s3; }
    }
    __syncthreads();
    unsigned cb = scal[0], countHigh = scal[1], countAt = scal[2];
    unsigned cut8 = 0;
    if (countAt > CAP) {
        if (tid < 256) aux[tid] = 0u;
        __syncthreads();
        for (int p = tid; p < NP; p += NT) {
            float v = src[(size_t)p * 93];
            float m = (v > 0.01f) ? v : -1.0f;
            unsigned k = f2ord(m);
            if (bin16(k) == cb) atomicAdd(&aux[(k >> 8) & 255u], 1u);
        }
        __syncthreads();
        for (int d = 1; d < 256; d <<= 1) {
            unsigned v = 0u;
            if (tid < 256 && tid + d < 256) v = aux[tid + d];
            __syncthreads();
            if (tid < 256) aux[tid] += v;
            __syncthreads();
        }
        if (tid < 256) {
            unsigned suf8 = aux[tid];
            unsigned sufN = (tid < 255) ? aux[tid + 1] : 0u;
            unsigned need2 = needed - countHigh;
            if (suf8 >= need2 && sufN < need2) scal[3] = (unsigned)tid;
        }
        __syncthreads();
        cut8 = scal[3];
    }
    __syncthreads();
    if (tid == 0) scal[1] = 0u;
    __syncthreads();
    for (int p = tid; p < NP; p += NT) {
        float v = src[(size_t)p * 93];
        float m = (v > 0.01f) ? v : -1.0f;
        unsigned key = f2ord(m);
        unsigned b16 = bin16(key);
        bool take = (b16 > cb) || (b16 == cb && ((key >> 8) & 255u) >= cut8);
        if (take) {
            unsigned pos = atomicAdd(&scal[1], 1u);
            if (pos < CAP) cand[pos] = ((unsigned long long)key << 32) | (unsigned)(~p);
        }
    }
    __syncthreads();
    unsigned cc = scal[1]; if (cc > CAP) cc = CAP;
    for (unsigned i = tid; i < CAP; i += NT) if (i >= cc) cand[i] = 0ull;
    __syncthreads();
    bitonic_desc(cand, (cc <= 512u) ? 512u : (unsigned)CAP, tid);
}

// -------- kNms: bucket wave-sort (0 barriers), tiled IoU, prefetch NMS -----
union ScratchU {
    unsigned long long sc[1024];                 // regsort scratch (fallback)
    unsigned iouRowP[WTASK];                     // packed triangular IoU bits
    struct { unsigned long long cand[CAP]; unsigned hist[1024]; unsigned aux[256]; } fb;
};

__global__ __launch_bounds__(NT) void kNms(const float* __restrict__ x,
                                           const float4* __restrict__ boxes,
                                           const unsigned long long* __restrict__ pcand,
                                           const unsigned* __restrict__ ccnt,
                                           const unsigned* __restrict__ gflag,
                                           unsigned long long* __restrict__ ckeys,
                                           float4* __restrict__ cboxesC,
                                           unsigned* __restrict__ kcnt) {
    __shared__ ScratchU U;
    __shared__ float4 selBox[SELN];      // skewed (SKW) layout
    __shared__ float selArea[SELN];
    __shared__ unsigned selKey[SELN];
    __shared__ unsigned short taskGW[TILN];   // (g<<4)|w per 4x32 IoU tile
    __shared__ unsigned csub[SUBS];
    __shared__ unsigned scal[4];
    __shared__ unsigned Vsh;             // # valid rows among top-400
    __shared__ unsigned keptWords[13];

    int b = blockIdx.x / NCLS, c = blockIdx.x % NCLS;
    int tid = threadIdx.x;
    unsigned t = (unsigned)tid;

    if (tid == 0) Vsh = 0u;
    // build tile table: group g (rows 4g..4g+3, all in band v=g>>3) has v+1 words
    if (tid < 100) {
        unsigned g = t, v = g >> 3, r = g & 7u;
        unsigned O = g + 4u * v * (v - 1u) + r * v;   // prefix of words
        for (unsigned w = 0; w <= v; ++w)
            taskGW[O + w] = (unsigned short)((g << 4) | w);
    }
    // bucket counts: clamp to SUBCAP (raw may exceed on overflow; gflag covers)
    if (tid < SUBS) {
        unsigned v = ccnt[((b * NCLS + c) * SUBS + t) * CSTR];
        csub[t] = (v > SUBCAP) ? (unsigned)SUBCAP : v;
    }
    unsigned gf = gflag[b * NCLS + c];
    __syncthreads();
    unsigned total = csub[0] + csub[1] + csub[2] + csub[3]
                   + csub[4] + csub[5] + csub[6] + csub[7];

    bool fast = (gf == 0u) && (total >= TOPK);   // total <= 1024 by construction
    if (fast) {
        // wave w owns bucket w: load its 128 slots (2/lane), mask stale tail,
        // wave-local sort (NO barriers), global rank = suffix-offset + index.
        const ulonglong2* src2 =
            (const ulonglong2*)(pcand + ((size_t)(b * NCLS + c) << 10));
        ulonglong2 vv = src2[t];
        unsigned s = t >> 6;               // bucket = wave index
        unsigned lane = t & 63u;
        unsigned e0 = 2u * lane;           // element index within bucket
        unsigned cs = csub[s];
        unsigned long long a0 = (e0     < cs) ? vv.x : 0ull;
        unsigned long long a1 = (e0 + 1 < cs) ? vv.y : 0ull;
        wave_sort128(a0, a1, lane);
        unsigned off = 0;
#pragma unroll
        for (unsigned b2 = 0; b2 < SUBS; ++b2) if (b2 > s) off += csub[b2];
        unsigned r0 = off + e0, r1 = off + e0 + 1u;
        if (e0 < cs && r0 < TOPK) {
            unsigned i0 = ~(unsigned)a0; if (i0 >= NP) i0 = 0;
            float4 bx = boxes[(size_t)b * NP + i0];
            selBox[SKW(r0)] = bx;
            selArea[SKW(r0)] = (bx.z - bx.x) * (bx.w - bx.y);
            selKey[SKW(r0)] = (unsigned)(a0 >> 32);
        }
        if (e0 + 1 < cs && r1 < TOPK) {
            unsigned i1 = ~(unsigned)a1; if (i1 >= NP) i1 = 0;
            float4 bx = boxes[(size_t)b * NP + i1];
            selBox[SKW(r1)] = bx;
            selArea[SKW(r1)] = (bx.z - bx.x) * (bx.w - bx.y);
            selKey[SKW(r1)] = (unsigned)(a1 >> 32);
        }
        if (tid == 0) Vsh = TOPK;          // all fast-path scores > T0 >> 0.01
    } else {    // exact fallback
        select_strided(x + (size_t)b * NP * 93 + 5 + c, TOPK,
                       U.fb.cand, U.fb.hist, U.fb.aux, scal, tid);
        unsigned long long a0 = U.fb.cand[2u * t];
        unsigned long long a1 = U.fb.cand[2u * t + 1];
        const unsigned VALID_KEY = f2ord(0.01f);
        if (t < TOPK / 2) {
            unsigned i0 = ~(unsigned)a0; if (i0 >= NP) i0 = 0;
            unsigned i1 = ~(unsigned)a1; if (i1 >= NP) i1 = 0;
            float4 b0 = boxes[(size_t)b * NP + i0];
            float4 b1 = boxes[(size_t)b * NP + i1];
            selBox[SKW(2u * t)] = b0;            selBox[SKW(2u * t + 1)] = b1;
            selArea[SKW(2u * t)] = (b0.z - b0.x) * (b0.w - b0.y);
            selArea[SKW(2u * t + 1)] = (b1.z - b1.x) * (b1.w - b1.y);
            selKey[SKW(2u * t)] = (unsigned)(a0 >> 32);
            selKey[SKW(2u * t + 1)] = (unsigned)(a1 >> 32);
        }
        bool v0 = (t < TOPK / 2) && ((unsigned)(a0 >> 32) > VALID_KEY);
        bool v1 = (t < TOPK / 2) && ((unsigned)(a1 >> 32) > VALID_KEY);
        unsigned long long bv0 = __ballot(v0), bv1 = __ballot(v1);
        if ((t & 63u) == 0u)
            atomicAdd(&Vsh, (unsigned)(__popcll(bv0) + __popcll(bv1)));
    }
    __syncthreads();

    // 4-row x 32-col tiled IoU: col reads amortize over 4 rows.
    for (int T = tid; T < TILN; T += NT) {
        unsigned gw = (unsigned)taskGW[T];
        unsigned g = gw >> 4, w = gw & 15u;
        unsigned r0 = 4u * g;
        float4 br0 = selBox[SKW(r0)];     float ar0 = selArea[SKW(r0)];
        float4 br1 = selBox[SKW(r0 + 1)]; float ar1 = selArea[SKW(r0 + 1)];
        float4 br2 = selBox[SKW(r0 + 2)]; float ar2 = selArea[SKW(r0 + 2)];
        float4 br3 = selBox[SKW(r0 + 3)]; float ar3 = selArea[SKW(r0 + 3)];
        unsigned w0 = 0, w1 = 0, w2 = 0, w3 = 0;
#pragma unroll 8
        for (int jj = 0; jj < 32; ++jj) {
            int j = (int)(w * 32u) + jj;
            float4 bj = selBox[SKW(j)];
            float aj = selArea[SKW(j)];
#define IOU1(BR, AR, WRD) { \
            float ix = fminf(BR.z, bj.z) - fmaxf(BR.x, bj.x); \
            float iy = fminf(BR.w, bj.w) - fmaxf(BR.y, bj.y); \
            float inter = fmaxf(ix, 0.f) * fmaxf(iy, 0.f); \
            float uni = AR + aj - inter; \
            WRD |= (unsigned)(inter > 0.45f * uni) << jj; }
            IOU1(br0, ar0, w0) IOU1(br1, ar1, w1)
            IOU1(br2, ar2, w2) IOU1(br3, ar3, w3)
#undef IOU1
        }
        unsigned band = g >> 3;
        unsigned baseo = (band + 1u) * (16u * band + (r0 & 31u)) + w;
        U.iouRowP[baseo]                   = w0;   // rowOff(r)+w, packed layout
        U.iouRowP[baseo +      (band + 1u)] = w1;
        U.iouRowP[baseo + 2u * (band + 1u)] = w2;
        U.iouRowP[baseo + 3u * (band + 1u)] = w3;
    }
    __syncthreads();

    if (tid < 64) {    // NMS scan: 8-deep static-reg prefetch hides LDS latency
        unsigned lane = t;
        unsigned myKept = 0;
        unsigned V = Vsh;
        unsigned q0 = U.iouRowP[0 + lane], q1 = U.iouRowP[1 + lane];
        unsigned q2 = U.iouRowP[2 + lane], q3 = U.iouRowP[3 + lane];
        unsigned q4 = U.iouRowP[4 + lane], q5 = U.iouRowP[5 + lane];
        unsigned q6 = U.iouRowP[6 + lane], q7 = U.iouRowP[7 + lane];
        // garbage lanes (lane > band) are safe: their myKept bits are 0.
#define STEP(Q, II) { \
        unsigned w_ = Q; \
        int ip_ = (II) + 8; \
        if (ip_ < TOPK) { \
            unsigned bb_ = (unsigned)ip_ >> 5; \
            Q = U.iouRowP[(bb_ + 1u) * (16u * bb_ + ((unsigned)ip_ & 31u)) + lane]; \
        } \
        bool hit_ = (w_ & myKept) != 0u; \
        unsigned long long bal_ = __ballot(hit_); \
        if ((unsigned)(II) < V && bal_ == 0ull && lane == ((unsigned)(II) >> 5)) \
            myKept |= 1u << ((II) & 31); }
        for (int i = 0; i < TOPK; i += 8) {
            STEP(q0, i)     STEP(q1, i + 1) STEP(q2, i + 2) STEP(q3, i + 3)
            STEP(q4, i + 4) STEP(q5, i + 5) STEP(q6, i + 6) STEP(q7, i + 7)
        }
#undef STEP
        if (lane < 13) keptWords[lane] = myKept;
    }
    __syncthreads();

    // epilogue: ONE reservation atomic; write ONLY kept dets (key + box).
    // low32 = ~((c<<16)|idx): ties sort c asc then idx asc == old flat order.
    if (tid == 0) {
        unsigned total2 = 0;
        for (int w = 0; w < 13; ++w) total2 += __popc(keptWords[w]);
        scal[2] = atomicAdd(&kcnt[b * 16], total2);
    }
    __syncthreads();
    unsigned base = scal[2];
    size_t kb = (size_t)b * CKS;
    for (int k = tid; k < TOPK; k += NT) {
        bool kept = (keptWords[k >> 5] >> (k & 31)) & 1u;
        if (kept) {
            unsigned rank = 0;
            int wi = k >> 5;
            for (int w = 0; w < wi; ++w) rank += __popc(keptWords[w]);
            rank += __popc(keptWords[wi] & ((1u << (k & 31)) - 1u));
            unsigned idx = base + rank;
            ckeys[kb + idx] =
                ((unsigned long long)selKey[SKW(k)] << 32) |
                (unsigned)(~(((unsigned)c << 16) | idx));
            cboxesC[kb + idx] = selBox[SKW(k)];
        }
    }
}

// -------- kC: per-batch top-200 of compacted keys + rasterize --------------
struct HistU { unsigned hist[1024]; unsigned aux[256]; };

__global__ __launch_bounds__(NT) void kC(const unsigned long long* __restrict__ ckeys,
                                         const float4* __restrict__ cboxesC,
                                         const unsigned* __restrict__ kcnt,
                                         float* __restrict__ out) {
    __shared__ unsigned long long cand[CAP];
    __shared__ unsigned long long scK[CAP];     // regsort scratch
    __shared__ HistU S;
    __shared__ unsigned scal[4];
    __shared__ float eS[KEEPK];
    __shared__ int eC0[KEEPK], eC1[KEEPK], eC2[KEEPK], eC3[KEEPK];
    __shared__ int eCh[KEEPK];

    int b = blockIdx.x;
    int tid = threadIdx.x;
    unsigned t = (unsigned)tid;
    const ulonglong2* k2 = (const ulonglong2*)(ckeys + (size_t)b * CKS);
    int n = (int)kcnt[b * 16]; if (n > DETN) n = DETN;
    int n2 = (n + 1) >> 1;           // odd trailing slot masked below (no pre-zero)
    const unsigned needed = KEEPK;

    for (int i = tid; i < 1024; i += NT) S.hist[i] = 0u;
    if (tid == 0) { scal[0] = 0u; scal[1] = 0u; scal[2] = 0u; scal[3] = 0u; }
    __syncthreads();
    for (int i = tid; i < n2; i += NT) {
        ulonglong2 v = k2[i];
        atomicAdd(&S.hist[bin16((unsigned)(v.x >> 32))], 1u);
        if (2 * i + 1 < n) atomicAdd(&S.hist[bin16((unsigned)(v.y >> 32))], 1u);
    }
    __syncthreads();
    unsigned h0 = 0, h1 = 0, h2 = 0, h3 = 0;
    if (tid < 256) {
        h0 = S.hist[4 * tid]; h1 = S.hist[4 * tid + 1];
        h2 = S.hist[4 * tid + 2]; h3 = S.hist[4 * tid + 3];
        S.aux[tid] = h0 + h1 + h2 + h3;
    }
    __syncthreads();
    for (int d = 1; d < 256; d <<= 1) {
        unsigned v = 0u;
        if (tid < 256 && tid + d < 256) v = S.aux[tid + d];
        __syncthreads();
        if (tid < 256) S.aux[tid] += v;
        __syncthreads();
    }
    if (tid < 256) {
        unsigned above = (tid < 255) ? S.aux[tid + 1] : 0u;
        unsigned s3 = above + h3, s2 = s3 + h2, s1 = s2 + h1, s0 = s1 + h0;
        if (s0 >= needed && s1 < needed) { scal[0] = 4 * tid;     scal[1] = s1;    scal[2] = s0; }
        if (s1 >= needed && s2 < needed) { scal[0] = 4 * tid + 1; scal[1] = s2;    scal[2] = s1; }
        if (s2 >= needed && s3 < needed) { scal[0] = 4 * tid + 2; scal[1] = s3;    scal[2] = s2; }
        if (s3 >= needed && above < needed) { scal[0] = 4 * tid + 3; scal[1] = above; scal[2] = s3; }
    }
    __syncthreads();
    unsigned cb = scal[0], countHigh = scal[1], countAt = scal[2];
    unsigned cut8 = 0;
    if (countAt > CAP) {   // byte refine on key[15:8] within cut bin
        if (tid < 256) S.aux[tid] = 0u;
        __syncthreads();
        for (int i = tid; i < n2; i += NT) {
            ulonglong2 v = k2[i];
            unsigned kx = (unsigned)(v.x >> 32), ky = (unsigned)(v.y >> 32);
            if (bin16(kx) == cb) atomicAdd(&S.aux[(kx >> 8) & 255u], 1u);
            if (2 * i + 1 < n && bin16(ky) == cb) atomicAdd(&S.aux[(ky >> 8) & 255u], 1u);
        }
        __syncthreads();
        for (int d = 1; d < 256; d <<= 1) {
            unsigned v = 0u;
            if (tid < 256 && tid + d < 256) v = S.aux[tid + d];
            __syncthreads();
            if (tid < 256) S.aux[tid] += v;
            __syncthreads();
        }
        if (tid < 256) {
            unsigned suf8 = S.aux[tid];
            unsigned sufN = (tid < 255) ? S.aux[tid + 1] : 0u;
            unsigned need2 = needed - countHigh;
            if (suf8 >= need2 && sufN < need2) scal[3] = (unsigned)tid;
        }
        __syncthreads();
        cut8 = scal[3];
    }
    __syncthreads();
    if (tid == 0) scal[1] = 0u;
    __syncthreads();
    for (int i = tid; i < n2; i += NT) {
        ulonglong2 v = k2[i];
#pragma unroll
        for (int c = 0; c < 2; ++c) {
            if (c && 2 * i + 1 >= n) continue;
            unsigned long long key = c ? v.y : v.x;
            unsigned kh = (unsigned)(key >> 32);
            unsigned b16 = bin16(kh);
            bool take = (b16 > cb) || (b16 == cb && ((kh >> 8) & 255u) >= cut8);
            if (take) {
                unsigned pos = atomicAdd(&scal[1], 1u);
                if (pos < CAP) cand[pos] = key;
            }
        }
    }
    __syncthreads();
    unsigned cc = scal[1]; if (cc > CAP) cc = CAP;
    for (unsigned i = tid; i < CAP; i += NT) if (i >= cc) cand[i] = 0ull;
    __syncthreads();
    unsigned long long a0 = cand[2u * t], a1 = cand[2u * t + 1];
    __syncthreads();
    regsort1024(a0, a1, scK, t);

    if (t < KEEPK / 2) {     // thread t holds ranks 2t, 2t+1
#pragma unroll
        for (int q = 0; q < 2; ++q) {
            unsigned long long K = q ? a1 : a0;
            unsigned k = 2u * t + q;
            unsigned key = (unsigned)(K >> 32);
            unsigned lo = ~(unsigned)K;       // (c<<16)|idx
            unsigned ch = lo >> 16;
            unsigned idx = lo & 0xffffu;
            if (ch >= NCLS) { ch = 0; idx = 0; }   // padding guard
            float4 bx = cboxesC[(size_t)b * CKS + idx];
            eS[k] = (key == 0u) ? -1.0f : ord2f(key);
            eC0[k] = (int)rintf(bx.x * (float)OUTS);
            eC1[k] = (int)rintf(bx.y * (float)OUTS);
            eC2[k] = (int)rintf(bx.z * (float)OUTS);
            eC3[k] = (int)rintf(bx.w * (float)OUTS);
            eCh[k] = (int)ch;
        }
    }
    __syncthreads();

    for (int cell = tid; cell < NCELL; cell += NT) {
        int y = cell / OUTS, x = cell % OUTS;
        float* o = out + ((size_t)b * NCELL + cell) * 81;
        for (int ch = 0; ch < 81; ++ch) o[ch] = 0.f;
        for (int k = 0; k < KEEPK; ++k) {
            float s = eS[k];
            if (s < 0.6f) continue;
            if (y >= eC1[k] && y < eC3[k] && x >= eC0[k] && x < eC2[k])
                o[eCh[k]] = s;
        }
    }
}

extern "C" void kernel_launch(void* const* d_in, const int* in_sizes, int n_in,
                              void* d_out, int out_size, void* d_ws, size_t ws_size,
                              hipStream_t stream) {
    const float* x = (const float*)d_in[0];
    float* out = (float*)d_out;

    float4* boxes   = (float4*)d_ws;                          // NB*NP
    float4* cboxesC = boxes + (size_t)NB * NP;                // NB*CKS (compact kept boxes)
    unsigned long long* ckeys = (unsigned long long*)(cboxesC + (size_t)NB * CKS); // NB*CKS
    unsigned long long* pcand = ckeys + (size_t)NB * CKS;     // NB*NCLS*CAP
    unsigned* ccnt = (unsigned*)(pcand + ((size_t)NB * NCLS << 10));   // NB*NCLS*SUBS*CSTR
    unsigned* gflag = ccnt + NB * NCLS * SUBS * CSTR;         // NB*NCLS
    unsigned* kcnt  = gflag + NB * NCLS;                      // NB*16 (cacheline-padded)

    kZ<<<40, 256, 0, stream>>>(ccnt, gflag, kcnt);
    kA<<<NB * CHUNKS, NT, 0, stream>>>(x, boxes, pcand, ccnt, gflag);
    kNms<<<NB * NCLS, NT, 0, stream>>>(x, boxes, pcand, ccnt, gflag, ckeys, cboxesC, kcnt);
    kC<<<NB, NT, 0, stream>>>(ckeys, cboxesC, kcnt, out);
}

// Round 11
// 232.875 us; speedup vs baseline: 1.1637x; 1.1637x over previous
//
#include <hip/hip_runtime.h>

#define NB 8
#define NP 24564
#define NCLS 80          // foreground classes
#define TOPK 400
#define KEEPK 200
#define OUTS 19
#define NCELL (OUTS * OUTS)   // 361
#define DETN (NCLS * TOPK)    // 32000 per batch
#define CKS 32008             // compact-key stride per batch (16B-aligned)
#define ROWS 64
#define CHUNKS ((NP + ROWS - 1) / ROWS)   // 384
#define CAP 1024
#define T0 0.972f   // collection gate: E[count]=688 sd 26 -> count in [400,1024] w.h.p.
#define NT 512      // threads per block for kNms/kC/kA (8 waves)
#define LCAP 16     // per (chunk,class) LDS capacity: P(Binom(64,0.028)>16) ~ 1e-12
#define CSTR 16     // counter stride in u32 (64B = own cache line, kills atomic convoy)
#define SUBS 8      // sub-counters per (b,c): queue depth /8; sub = chunk&7
#define SUBCAP 128  // slots per sub (8*128 = 1024 = CAP); E=86 sd 9
#define WTASK 2704  // packed triangular IoU words: sum_{r<400} (r/32+1)
#define TILN 676    // 4-row x 32-col IoU tiles: sum_{g<100} (g/8+1)
// Skewed LDS index: for j=32w+jj, bank(4B)=(w+jj)%32 (conflict-free across w),
// bank-group(16B)=(w+jj)%8 (<=2-way = free). Same w -> same addr -> broadcast.
#define SKW(i) ((unsigned)(i) + ((unsigned)(i) >> 5))
#define SELN (TOPK + (TOPK >> 5) + 4)   // 416

__device__ __forceinline__ unsigned f2ord(float f) {
    unsigned u = __float_as_uint(f);
    return (u & 0x80000000u) ? ~u : (u | 0x80000000u);
}
__device__ __forceinline__ float ord2f(unsigned k) {
    unsigned u = (k & 0x80000000u) ? (k & 0x7fffffffu) : ~k;
    return __uint_as_float(u);
}
// 1024 bins over key top-16-bits; valid scores (0.01,1] map to [0x23,0x380].
__device__ __forceinline__ unsigned bin16(unsigned key) {
    int b = (int)(key >> 16) - 0xBC00;
    b = b < 0 ? 0 : (b > 1023 ? 1023 : b);
    return (unsigned)b;
}

__device__ __forceinline__ unsigned long long shfl_xor_u64(unsigned long long v, int mask) {
    unsigned lo = (unsigned)__shfl_xor((int)(unsigned)v, mask);
    unsigned hi = (unsigned)__shfl_xor((int)(v >> 32), mask);
    return ((unsigned long long)hi << 32) | lo;
}

// Register-resident bitonic sort, 1024 elems descending, 512 threads.
// Thread t holds elements e0=2t, e1=2t+1. Phases j<=64 intra-wave (shfl),
// j>=128 via LDS scratch sc[1024]. Only 6 LDS phases / 12 barriers total.
__device__ __forceinline__ void regsort1024(unsigned long long& a0, unsigned long long& a1,
                                            unsigned long long* sc, unsigned t) {
    const unsigned e0 = 2u * t;
#pragma unroll
    for (unsigned k = 2; k <= 1024; k <<= 1) {
#pragma unroll
        for (unsigned j = k >> 1; j >= 128; j >>= 1) {   // cross-wave via LDS
            sc[e0] = a0; sc[e0 + 1] = a1;
            __syncthreads();
            unsigned p0 = e0 ^ j;
            unsigned long long b0 = sc[p0], b1 = sc[p0 + 1];
            bool km = ((e0 & k) == 0u) ^ ((e0 & j) != 0u);
            a0 = km ? (a0 > b0 ? a0 : b0) : (a0 < b0 ? a0 : b0);
            a1 = km ? (a1 > b1 ? a1 : b1) : (a1 < b1 ? a1 : b1);
            __syncthreads();
        }
#pragma unroll
        for (unsigned j = ((k >> 1) < 64u ? (k >> 1) : 64u); j >= 2; j >>= 1) { // intra-wave
            unsigned long long b0 = shfl_xor_u64(a0, (int)(j >> 1));
            unsigned long long b1 = shfl_xor_u64(a1, (int)(j >> 1));
            bool km = ((e0 & k) == 0u) ^ ((e0 & j) != 0u);
            a0 = km ? (a0 > b0 ? a0 : b0) : (a0 < b0 ? a0 : b0);
            a1 = km ? (a1 > b1 ? a1 : b1) : (a1 < b1 ? a1 : b1);
        }
        {   // j == 1: in-thread
            bool dir = ((e0 & k) == 0u);
            unsigned long long mx = a0 > a1 ? a0 : a1;
            unsigned long long mn = a0 > a1 ? a1 : a0;
            a0 = dir ? mx : mn;
            a1 = dir ? mn : mx;
        }
    }
}

// LDS bitonic for the (near-never) exact fallback path only.
__device__ __forceinline__ void bitonic_desc(unsigned long long* cand, unsigned S, int tid) {
    for (unsigned k = 2; k <= S; k <<= 1)
        for (unsigned j = k >> 1; j; j >>= 1) {
            for (unsigned i = tid; i < S; i += NT) {
                unsigned l = i ^ j;
                if (l > i) {
                    unsigned long long a = cand[i], bq = cand[l];
                    bool sw = ((i & k) == 0) ? (a < bq) : (a > bq);
                    if (sw) { cand[i] = bq; cand[l] = a; }
                }
            }
            __syncthreads();
        }
}

// ------- kZ: zero counters + overflow flags --------------------------------
__global__ __launch_bounds__(256) void kZ(unsigned* __restrict__ ccnt,
                                          unsigned* __restrict__ gflag,
                                          unsigned* __restrict__ kcnt) {
    int t = blockIdx.x * 256 + threadIdx.x;
    for (int i = t; i < NB * NCLS * SUBS * CSTR; i += gridDim.x * 256) ccnt[i] = 0u;
    if (t < NB * NCLS) gflag[t] = 0u;
    if (t < NB * 16) kcnt[t] = 0u;
}

// ------- kA: decode boxes + LDS-local collect; sub-counter atomic burst ----
// sub = chunk&7: per-counter concurrency /8, each sub owns SUBCAP slots of
// the (b,c) slab. Atomics issue on waves 2-3 WHILE wave 0 decodes boxes.
__global__ __launch_bounds__(NT) void kA(const float* __restrict__ x,
                                         float4* __restrict__ boxes,
                                         unsigned long long* __restrict__ pcand,
                                         unsigned* __restrict__ ccnt,
                                         unsigned* __restrict__ gflag) {
    __shared__ float tile[ROWS * 93];
    __shared__ unsigned long long list[NCLS * LCAP];
    __shared__ unsigned lcnt[NCLS];
    __shared__ unsigned lbase[NCLS];

    int blk = blockIdx.x;
    int b = blk / CHUNKS, chunk = blk % CHUNKS;
    unsigned sub = (unsigned)(chunk & (SUBS - 1));
    int p0 = chunk * ROWS;
    int nrows = NP - p0; if (nrows > ROWS) nrows = ROWS;
    const float* src = x + (size_t)(b * NP + p0) * 93;
    int total4 = (nrows * 93) >> 2;          // 64*93 and 52*93 both %4==0
    const float4* s4 = (const float4*)src;
    float4* t4 = (float4*)tile;
    for (int e = threadIdx.x; e < total4; e += NT) t4[e] = s4[e];
    __syncthreads();

    int row = threadIdx.x & 63;              // lane == row
    int lane = row;
    int cg = threadIdx.x >> 6;               // 8 waves
    unsigned p = (unsigned)(p0 + row);
    bool rowOk = row < nrows;
    for (int c = cg; c < NCLS; c += (NT / 64)) {   // c uniform per wave, unique per block
        float v = rowOk ? tile[row * 93 + 5 + c] : -1.0f;
        bool pred = v > T0;
        unsigned long long bal = __ballot(pred);
        if (pred) {
            unsigned rank = (unsigned)__popcll(bal & ((1ull << lane) - 1ull));
            if (rank < LCAP)
                list[c * LCAP + rank] =
                    ((unsigned long long)f2ord(v) << 32) | (unsigned)(~p);
        }
        if (lane == 0) lcnt[c] = (unsigned)__popcll(bal);
    }
    __syncthreads();

    // waves 2-3: 80 parallel sub-counter atomics (hidden under decode on waves 0-1)
    if (threadIdx.x >= 128 && threadIdx.x < 128 + NCLS) {
        int c = threadIdx.x - 128;
        unsigned n = lcnt[c];
        unsigned wr = (n > LCAP) ? LCAP : n;
        unsigned old = 0u;
        if (wr) old = atomicAdd(&ccnt[((b * NCLS + c) * SUBS + sub) * CSTR], wr);
        lbase[c] = old;
        lcnt[c] = wr;
        if (n > LCAP || old + wr > SUBCAP) gflag[b * NCLS + c] = 1u;  // benign race
    }
    // wave 0 (concurrent with the atomics): decode + store boxes
    if (threadIdx.x < nrows) {
        const float* r = tile + threadIdx.x * 93;
        float l0 = r[0], l1 = r[1], l2 = r[2], l3 = r[3];
        float px1 = r[85], py1 = r[86], px2 = r[87], py2 = r[88];
        float v0 = r[89], v1 = r[90], v2 = r[91], v3 = r[92];
        float pw = px2 - px1, ph = py2 - py1;
        float pcx = 0.5f * (px2 + px1), pcy = 0.5f * (py2 + py1);
        float cx = l0 * pw * v0 + pcx;
        float cy = l1 * pw * v1 + pcy;      // reference uses pw here too
        float w = expf(l2 * v2) * pw;
        float h = expf(l3 * v3) * ph;
        float x1 = fminf(fmaxf(cx - 0.5f * w, 0.f), 1.f);
        float y1 = fminf(fmaxf(cy - 0.5f * h, 0.f), 1.f);
        float x2 = fminf(fmaxf(cx + 0.5f * w, 0.f), 1.f);
        float y2 = fminf(fmaxf(cy + 0.5f * h, 0.f), 1.f);
        boxes[(size_t)b * NP + p0 + threadIdx.x] = make_float4(x1, y1, x2, y2);
    }
    __syncthreads();

    for (int idx = threadIdx.x; idx < NCLS * LCAP; idx += NT) {
        int c = idx >> 4, i = idx & (LCAP - 1);
        if ((unsigned)i < lcnt[c]) {
            unsigned pos = lbase[c] + (unsigned)i;
            if (pos < SUBCAP)   // overflow -> gflag -> exact fallback path
                pcand[((size_t)(b * NCLS + c) << 10) + sub * SUBCAP + pos] = list[idx];
        }
    }
}

// --- exact fallback select: strided masked read of x, hist1024 + refine ----
__device__ void select_strided(const float* __restrict__ src, unsigned needed,
                               unsigned long long* cand,
                               unsigned* hist, unsigned* aux, unsigned* scal,
                               int tid) {
    for (int i = tid; i < 1024; i += NT) hist[i] = 0u;
    if (tid == 0) { scal[0] = 0u; scal[1] = 0u; scal[2] = 0u; scal[3] = 0u; }
    __syncthreads();
    for (int p = tid; p < NP; p += NT) {
        float v = src[(size_t)p * 93];
        float m = (v > 0.01f) ? v : -1.0f;
        atomicAdd(&hist[bin16(f2ord(m))], 1u);
    }
    __syncthreads();
    unsigned h0 = 0, h1 = 0, h2 = 0, h3 = 0;
    if (tid < 256) {
        h0 = hist[4 * tid]; h1 = hist[4 * tid + 1];
        h2 = hist[4 * tid + 2]; h3 = hist[4 * tid + 3];
        aux[tid] = h0 + h1 + h2 + h3;
    }
    __syncthreads();
    for (int d = 1; d < 256; d <<= 1) {
        unsigned v = 0u;
        if (tid < 256 && tid + d < 256) v = aux[tid + d];
        __syncthreads();
        if (tid < 256) aux[tid] += v;
        __syncthreads();
    }
    if (tid < 256) {
        unsigned above = (tid < 255) ? aux[tid + 1] : 0u;
        unsigned s3 = above + h3, s2 = s3 + h2, s1 = s2 + h1, s0 = s1 + h0;
        if (s0 >= needed && s1 < needed) { scal[0] = 4 * tid;     scal[1] = s1;    scal[2] = s0; }
        if (s1 >= needed && s2 < needed) { scal[0] = 4 * tid + 1; scal[1] = s2;    scal[2] = s1; }
        if (s2 >= needed && s3 < needed) { scal[0] = 4 * tid + 2; scal[1] = s3;    scal[2] = s2; }
        if (s3 >= needed && above < needed) { scal[0] = 4 * tid + 3; scal[1] = above; scal[2] = s3; }
    }
    __syncthreads();
    unsigned cb = scal[0], countHigh = scal[1], countAt = scal[2];
    unsigned cut8 = 0;
    if (countAt > CAP) {
        if (tid < 256) aux[tid] = 0u;
        __syncthreads();
        for (int p = tid; p < NP; p += NT) {
            float v = src[(size_t)p * 93];
            float m = (v > 0.01f) ? v : -1.0f;
            unsigned k = f2ord(m);
            if (bin16(k) == cb) atomicAdd(&aux[(k >> 8) & 255u], 1u);
        }
        __syncthreads();
        for (int d = 1; d < 256; d <<= 1) {
            unsigned v = 0u;
            if (tid < 256 && tid + d < 256) v = aux[tid + d];
            __syncthreads();
            if (tid < 256) aux[tid] += v;
            __syncthreads();
        }
        if (tid < 256) {
            unsigned suf8 = aux[tid];
            unsigned sufN = (tid < 255) ? aux[tid + 1] : 0u;
            unsigned need2 = needed - countHigh;
            if (suf8 >= need2 && sufN < need2) scal[3] = (unsigned)tid;
        }
        __syncthreads();
        cut8 = scal[3];
    }
    __syncthreads();
    if (tid == 0) scal[1] = 0u;
    __syncthreads();
    for (int p = tid; p < NP; p += NT) {
        float v = src[(size_t)p * 93];
        float m = (v > 0.01f) ? v : -1.0f;
        unsigned key = f2ord(m);
        unsigned b16 = bin16(key);
        bool take = (b16 > cb) || (b16 == cb && ((key >> 8) & 255u) >= cut8);
        if (take) {
            unsigned pos = atomicAdd(&scal[1], 1u);
            if (pos < CAP) cand[pos] = ((unsigned long long)key << 32) | (unsigned)(~p);
        }
    }
    __syncthreads();
    unsigned cc = scal[1]; if (cc > CAP) cc = CAP;
    for (unsigned i = tid; i < CAP; i += NT) if (i >= cc) cand[i] = 0ull;
    __syncthreads();
    bitonic_desc(cand, (cc <= 512u) ? 512u : (unsigned)CAP, tid);
}

// -------- kNms: reg-load, reg-sort, 4-row tiled IoU, deep-prefetch NMS -----
union ScratchU {
    unsigned long long sc[1024];                 // regsort cross-wave scratch
    unsigned iouRowP[WTASK];                     // packed triangular IoU bits
    struct { unsigned long long cand[CAP]; unsigned hist[1024]; unsigned aux[256]; } fb;
};

__global__ __launch_bounds__(NT) void kNms(const float* __restrict__ x,
                                           const float4* __restrict__ boxes,
                                           const unsigned long long* __restrict__ pcand,
                                           const unsigned* __restrict__ ccnt,
                                           const unsigned* __restrict__ gflag,
                                           unsigned long long* __restrict__ ckeys,
                                           float4* __restrict__ cboxes,
                                           unsigned* __restrict__ kcnt) {
    __shared__ ScratchU U;
    __shared__ float4 selBox[SELN];      // skewed (SKW) layout
    __shared__ float selArea[SELN];
    __shared__ unsigned selKey[SELN];
    __shared__ unsigned short taskGW[TILN];   // (g<<4)|w per 4x32 IoU tile
    __shared__ unsigned csub[SUBS];
    __shared__ unsigned scal[4];
    __shared__ unsigned Vsh;             // # valid rows (score>0.01) among top-400
    __shared__ unsigned keptWords[13];

    int b = blockIdx.x / NCLS, c = blockIdx.x % NCLS;
    int tid = threadIdx.x;
    unsigned t = (unsigned)tid;

    if (tid == 0) Vsh = 0u;
    // build tile table: group g (rows 4g..4g+3, all in band v=g>>3) has v+1 words
    if (tid < 100) {
        unsigned g = t, v = g >> 3, r = g & 7u;
        unsigned O = g + 4u * v * (v - 1u) + r * v;   // prefix of words
        for (unsigned w = 0; w <= v; ++w)
            taskGW[O + w] = (unsigned short)((g << 4) | w);
    }
    // sub-counters: clamp to SUBCAP (raw may exceed on overflow; gflag covers)
    if (tid < SUBS) {
        unsigned v = ccnt[((b * NCLS + c) * SUBS + t) * CSTR];
        csub[t] = (v > SUBCAP) ? (unsigned)SUBCAP : v;
    }
    unsigned gf = gflag[b * NCLS + c];
    __syncthreads();
    unsigned total = csub[0] + csub[1] + csub[2] + csub[3]
                   + csub[4] + csub[5] + csub[6] + csub[7];

    bool fast = (gf == 0u) && (total >= TOPK);   // total <= 1024 by construction
    unsigned long long a0, a1;
    if (fast) {
        const ulonglong2* src2 =
            (const ulonglong2*)(pcand + ((size_t)(b * NCLS + c) << 10));
        ulonglong2 vv = src2[t];           // coalesced 16B; mask stale per-sub tail
        unsigned s = t >> 6;               // both elems in sub s (SUBCAP=128)
        unsigned o0 = (2u * t) & (SUBCAP - 1u);
        unsigned cs = csub[s];
        a0 = (o0     < cs) ? vv.x : 0ull;
        a1 = (o0 + 1 < cs) ? vv.y : 0ull;
        regsort1024(a0, a1, U.sc, t);      // gaps sort to the end (keys unique)
    } else {    // exact fallback
        select_strided(x + (size_t)b * NP * 93 + 5 + c, TOPK,
                       U.fb.cand, U.fb.hist, U.fb.aux, scal, tid);
        a0 = U.fb.cand[2u * t];
        a1 = U.fb.cand[2u * t + 1];
    }
    const unsigned VALID_KEY = f2ord(0.01f);
    // thread t holds ranks 2t, 2t+1 (descending)
    if (t < TOPK / 2) {
        unsigned i0 = ~(unsigned)a0; if (i0 >= NP) i0 = 0;
        unsigned i1 = ~(unsigned)a1; if (i1 >= NP) i1 = 0;
        float4 b0 = boxes[(size_t)b * NP + i0];
        float4 b1 = boxes[(size_t)b * NP + i1];
        selBox[SKW(2u * t)] = b0;            selBox[SKW(2u * t + 1)] = b1;
        selArea[SKW(2u * t)] = (b0.z - b0.x) * (b0.w - b0.y);
        selArea[SKW(2u * t + 1)] = (b1.z - b1.x) * (b1.w - b1.y);
        selKey[SKW(2u * t)] = (unsigned)(a0 >> 32);
        selKey[SKW(2u * t + 1)] = (unsigned)(a1 >> 32);
    }
    // V = count of valid keys in top-400 (sorted desc -> validity is a prefix)
    {
        bool v0 = (t < TOPK / 2) && ((unsigned)(a0 >> 32) > VALID_KEY);
        bool v1 = (t < TOPK / 2) && ((unsigned)(a1 >> 32) > VALID_KEY);
        unsigned long long bv0 = __ballot(v0), bv1 = __ballot(v1);
        if ((t & 63u) == 0u)
            atomicAdd(&Vsh, (unsigned)(__popcll(bv0) + __popcll(bv1)));
    }
    __syncthreads();

    // 4-row x 32-col tiled IoU: col reads amortize over 4 rows.
    for (int T = tid; T < TILN; T += NT) {
        unsigned gw = (unsigned)taskGW[T];
        unsigned g = gw >> 4, w = gw & 15u;
        unsigned r0 = 4u * g;
        float4 br0 = selBox[SKW(r0)];     float ar0 = selArea[SKW(r0)];
        float4 br1 = selBox[SKW(r0 + 1)]; float ar1 = selArea[SKW(r0 + 1)];
        float4 br2 = selBox[SKW(r0 + 2)]; float ar2 = selArea[SKW(r0 + 2)];
        float4 br3 = selBox[SKW(r0 + 3)]; float ar3 = selArea[SKW(r0 + 3)];
        unsigned w0 = 0, w1 = 0, w2 = 0, w3 = 0;
#pragma unroll 8
        for (int jj = 0; jj < 32; ++jj) {
            int j = (int)(w * 32u) + jj;
            float4 bj = selBox[SKW(j)];
            float aj = selArea[SKW(j)];
#define IOU1(BR, AR, WRD) { \
            float ix = fminf(BR.z, bj.z) - fmaxf(BR.x, bj.x); \
            float iy = fminf(BR.w, bj.w) - fmaxf(BR.y, bj.y); \
            float inter = fmaxf(ix, 0.f) * fmaxf(iy, 0.f); \
            float uni = AR + aj - inter; \
            WRD |= (unsigned)(inter > 0.45f * uni) << jj; }
            IOU1(br0, ar0, w0) IOU1(br1, ar1, w1)
            IOU1(br2, ar2, w2) IOU1(br3, ar3, w3)
#undef IOU1
        }
        unsigned band = g >> 3;
        unsigned baseo = (band + 1u) * (16u * band + (r0 & 31u)) + w;
        U.iouRowP[baseo]                   = w0;   // rowOff(r)+w, packed layout
        U.iouRowP[baseo +      (band + 1u)] = w1;
        U.iouRowP[baseo + 2u * (band + 1u)] = w2;
        U.iouRowP[baseo + 3u * (band + 1u)] = w3;
    }
    __syncthreads();

    if (tid < 64) {    // NMS scan: 8-deep static-reg prefetch hides LDS latency
        unsigned lane = t;
        unsigned myKept = 0;
        unsigned V = Vsh;
        unsigned q0 = U.iouRowP[0 + lane], q1 = U.iouRowP[1 + lane];
        unsigned q2 = U.iouRowP[2 + lane], q3 = U.iouRowP[3 + lane];
        unsigned q4 = U.iouRowP[4 + lane], q5 = U.iouRowP[5 + lane];
        unsigned q6 = U.iouRowP[6 + lane], q7 = U.iouRowP[7 + lane];
        // garbage lanes (lane > band) are safe: their myKept bits are 0.
#define STEP(Q, II) { \
        unsigned w_ = Q; \
        int ip_ = (II) + 8; \
        if (ip_ < TOPK) { \
            unsigned bb_ = (unsigned)ip_ >> 5; \
            Q = U.iouRowP[(bb_ + 1u) * (16u * bb_ + ((unsigned)ip_ & 31u)) + lane]; \
        } \
        bool hit_ = (w_ & myKept) != 0u; \
        unsigned long long bal_ = __ballot(hit_); \
        if ((unsigned)(II) < V && bal_ == 0ull && lane == ((unsigned)(II) >> 5)) \
            myKept |= 1u << ((II) & 31); }
        for (int i = 0; i < TOPK; i += 8) {
            STEP(q0, i)     STEP(q1, i + 1) STEP(q2, i + 2) STEP(q3, i + 3)
            STEP(q4, i + 4) STEP(q5, i + 5) STEP(q6, i + 6) STEP(q7, i + 7)
        }
#undef STEP
        if (lane < 13) keptWords[lane] = myKept;
    }
    __syncthreads();

    // epilogue: ONE reservation atomic per block, rank-indexed writes
    if (tid == 0) {
        unsigned total2 = 0;
        for (int w = 0; w < 13; ++w) total2 += __popc(keptWords[w]);
        scal[2] = atomicAdd(&kcnt[b * 16], total2);
    }
    __syncthreads();
    unsigned base = scal[2];
    size_t kb = (size_t)b * CKS;
    size_t bb = (size_t)b * DETN;
    for (int k = tid; k < TOPK; k += NT) {
        unsigned flat = (unsigned)(c * TOPK + k);
        cboxes[bb + flat] = selBox[SKW(k)];
        bool kept = (keptWords[k >> 5] >> (k & 31)) & 1u;
        if (kept) {
            unsigned rank = 0;
            int wi = k >> 5;
            for (int w = 0; w < wi; ++w) rank += __popc(keptWords[w]);
            rank += __popc(keptWords[wi] & ((1u << (k & 31)) - 1u));
            ckeys[kb + base + rank] =
                ((unsigned long long)selKey[SKW(k)] << 32) | (unsigned)(~flat);
        }
    }
}

// -------- kC: per-batch top-200 of compacted keys + rasterize --------------
struct HistU { unsigned hist[1024]; unsigned aux[256]; };

__global__ __launch_bounds__(NT) void kC(const unsigned long long* __restrict__ ckeys,
                                         const float4* __restrict__ cboxes,
                                         const unsigned* __restrict__ kcnt,
                                         float* __restrict__ out) {
    __shared__ unsigned long long cand[CAP];
    __shared__ unsigned long long scK[CAP];     // regsort scratch (LDS plentiful here)
    __shared__ HistU S;
    __shared__ unsigned scal[4];
    __shared__ float eS[KEEPK];
    __shared__ int eC0[KEEPK], eC1[KEEPK], eC2[KEEPK], eC3[KEEPK];
    __shared__ int eCh[KEEPK];

    int b = blockIdx.x;
    int tid = threadIdx.x;
    unsigned t = (unsigned)tid;
    const ulonglong2* k2 = (const ulonglong2*)(ckeys + (size_t)b * CKS);
    int n = (int)kcnt[b * 16]; if (n > DETN) n = DETN;
    int n2 = (n + 1) >> 1;           // odd trailing slot masked below (no pre-zero)
    const unsigned needed = KEEPK;

    for (int i = tid; i < 1024; i += NT) S.hist[i] = 0u;
    if (tid == 0) { scal[0] = 0u; scal[1] = 0u; scal[2] = 0u; scal[3] = 0u; }
    __syncthreads();
    for (int i = tid; i < n2; i += NT) {
        ulonglong2 v = k2[i];
        atomicAdd(&S.hist[bin16((unsigned)(v.x >> 32))], 1u);
        if (2 * i + 1 < n) atomicAdd(&S.hist[bin16((unsigned)(v.y >> 32))], 1u);
    }
    __syncthreads();
    unsigned h0 = 0, h1 = 0, h2 = 0, h3 = 0;
    if (tid < 256) {
        h0 = S.hist[4 * tid]; h1 = S.hist[4 * tid + 1];
        h2 = S.hist[4 * tid + 2]; h3 = S.hist[4 * tid + 3];
        S.aux[tid] = h0 + h1 + h2 + h3;
    }
    __syncthreads();
    for (int d = 1; d < 256; d <<= 1) {
        unsigned v = 0u;
        if (tid < 256 && tid + d < 256) v = S.aux[tid + d];
        __syncthreads();
        if (tid < 256) S.aux[tid] += v;
        __syncthreads();
    }
    if (tid < 256) {
        unsigned above = (tid < 255) ? S.aux[tid + 1] : 0u;
        unsigned s3 = above + h3, s2 = s3 + h2, s1 = s2 + h1, s0 = s1 + h0;
        if (s0 >= needed && s1 < needed) { scal[0] = 4 * tid;     scal[1] = s1;    scal[2] = s0; }
        if (s1 >= needed && s2 < needed) { scal[0] = 4 * tid + 1; scal[1] = s2;    scal[2] = s1; }
        if (s2 >= needed && s3 < needed) { scal[0] = 4 * tid + 2; scal[1] = s3;    scal[2] = s2; }
        if (s3 >= needed && above < needed) { scal[0] = 4 * tid + 3; scal[1] = above; scal[2] = s3; }
    }
    __syncthreads();
    unsigned cb = scal[0], countHigh = scal[1], countAt = scal[2];
    unsigned cut8 = 0;
    if (countAt > CAP) {   // byte refine on key[15:8] within cut bin
        if (tid < 256) S.aux[tid] = 0u;
        __syncthreads();
        for (int i = tid; i < n2; i += NT) {
            ulonglong2 v = k2[i];
            unsigned kx = (unsigned)(v.x >> 32), ky = (unsigned)(v.y >> 32);
            if (bin16(kx) == cb) atomicAdd(&S.aux[(kx >> 8) & 255u], 1u);
            if (2 * i + 1 < n && bin16(ky) == cb) atomicAdd(&S.aux[(ky >> 8) & 255u], 1u);
        }
        __syncthreads();
        for (int d = 1; d < 256; d <<= 1) {
            unsigned v = 0u;
            if (tid < 256 && tid + d < 256) v = S.aux[tid + d];
            __syncthreads();
            if (tid < 256) S.aux[tid] += v;
            __syncthreads();
        }
        if (tid < 256) {
            unsigned suf8 = S.aux[tid];
            unsigned sufN = (tid < 255) ? S.aux[tid + 1] : 0u;
            unsigned need2 = needed - countHigh;
            if (suf8 >= need2 && sufN < need2) scal[3] = (unsigned)tid;
        }
        __syncthreads();
        cut8 = scal[3];
    }
    __syncthreads();
    if (tid == 0) scal[1] = 0u;
    __syncthreads();
    for (int i = tid; i < n2; i += NT) {
        ulonglong2 v = k2[i];
#pragma unroll
        for (int c = 0; c < 2; ++c) {
            if (c && 2 * i + 1 >= n) continue;
            unsigned long long key = c ? v.y : v.x;
            unsigned kh = (unsigned)(key >> 32);
            unsigned b16 = bin16(kh);
            bool take = (b16 > cb) || (b16 == cb && ((kh >> 8) & 255u) >= cut8);
            if (take) {
                unsigned pos = atomicAdd(&scal[1], 1u);
                if (pos < CAP) cand[pos] = key;
            }
        }
    }
    __syncthreads();
    unsigned cc = scal[1]; if (cc > CAP) cc = CAP;
    for (unsigned i = tid; i < CAP; i += NT) if (i >= cc) cand[i] = 0ull;
    __syncthreads();
    unsigned long long a0 = cand[2u * t], a1 = cand[2u * t + 1];
    __syncthreads();
    regsort1024(a0, a1, scK, t);

    if (t < KEEPK / 2) {     // thread t holds ranks 2t, 2t+1
#pragma unroll
        for (int q = 0; q < 2; ++q) {
            unsigned long long K = q ? a1 : a0;
            unsigned k = 2u * t + q;
            unsigned key = (unsigned)(K >> 32);
            unsigned flat = ~(unsigned)K;
            if (flat >= DETN) flat = 0;
            float4 bx = cboxes[(size_t)b * DETN + flat];
            eS[k] = (key == 0u) ? -1.0f : ord2f(key);
            eC0[k] = (int)rintf(bx.x * (float)OUTS);
            eC1[k] = (int)rintf(bx.y * (float)OUTS);
            eC2[k] = (int)rintf(bx.z * (float)OUTS);
            eC3[k] = (int)rintf(bx.w * (float)OUTS);
            eCh[k] = (int)(flat / TOPK);
        }
    }
    __syncthreads();

    for (int cell = tid; cell < NCELL; cell += NT) {
        int y = cell / OUTS, x = cell % OUTS;
        float* o = out + ((size_t)b * NCELL + cell) * 81;
        for (int ch = 0; ch < 81; ++ch) o[ch] = 0.f;
        for (int k = 0; k < KEEPK; ++k) {
            float s = eS[k];
            if (s < 0.6f) continue;
            if (y >= eC1[k] && y < eC3[k] && x >= eC0[k] && x < eC2[k])
                o[eCh[k]] = s;
        }
    }
}

extern "C" void kernel_launch(void* const* d_in, const int* in_sizes, int n_in,
                              void* d_out, int out_size, void* d_ws, size_t ws_size,
                              hipStream_t stream) {
    const float* x = (const float*)d_in[0];
    float* out = (float*)d_out;

    float4* boxes   = (float4*)d_ws;                          // NB*NP
    float4* cboxes  = boxes + (size_t)NB * NP;                // NB*DETN
    unsigned long long* ckeys = (unsigned long long*)(cboxes + (size_t)NB * DETN); // NB*CKS
    unsigned long long* pcand = ckeys + (size_t)NB * CKS;     // NB*NCLS*CAP
    unsigned* ccnt = (unsigned*)(pcand + ((size_t)NB * NCLS << 10));   // NB*NCLS*SUBS*CSTR
    unsigned* gflag = ccnt + NB * NCLS * SUBS * CSTR;         // NB*NCLS
    unsigned* kcnt  = gflag + NB * NCLS;                      // NB*16 (cacheline-padded)

    kZ<<<40, 256, 0, stream>>>(ccnt, gflag, kcnt);
    kA<<<NB * CHUNKS, NT, 0, stream>>>(x, boxes, pcand, ccnt, gflag);
    kNms<<<NB * NCLS, NT, 0, stream>>>(x, boxes, pcand, ccnt, gflag, ckeys, cboxes, kcnt);
    kC<<<NB, NT, 0, stream>>>(ckeys, cboxes, kcnt, out);
}